// Round 13
// baseline (524.641 us; speedup 1.0000x reference)
//
#include <hip/hip_runtime.h>
#include <cstdint>

// ChessRelativeTransformer on MI355X (gfx950), bf16 MFMA pipeline.
// B=512 T=64 H=16 DH=64 D=1024 NUM_REL=225 scale=0.125
// R13: k_cvt switched to grid-stride (2048 blocks, 16 quads/thread) --
//      32768 tiny workgroups had dispatch overhead + no per-thread load
//      pipelining; x-convert traffic floor is ~30us, was est. ~45.
//      Everything else identical to R12 (521us, absmax 1.95e-3).

typedef unsigned short u16;
typedef unsigned int u32;
typedef __bf16 bf16x8 __attribute__((ext_vector_type(8)));
typedef float f32x4 __attribute__((ext_vector_type(4)));

#define MFMA16(a, b, c) __builtin_amdgcn_mfma_f32_16x16x32_bf16(a, b, c, 0, 0, 0)
#define BAR __builtin_amdgcn_s_barrier()
#define LGK(n) asm volatile("s_waitcnt lgkmcnt(" #n ")" ::: "memory")
#define VMC(n) asm volatile("s_waitcnt vmcnt(" #n ")" ::: "memory")

__device__ __forceinline__ u16 f2bf(float f) {
  u32 u = __builtin_bit_cast(u32, f);
  u = (u + 0x7FFFu + ((u >> 16) & 1u)) >> 16;
  return (u16)u;
}
__device__ __forceinline__ float bf2f(u16 h) {
  return __builtin_bit_cast(float, ((u32)h) << 16);
}

__device__ __forceinline__ void g2l16(const void* g, void* lds_wave_base) {
#if __has_builtin(__builtin_amdgcn_global_load_lds)
  __builtin_amdgcn_global_load_lds(
      (const __attribute__((address_space(1))) u32*)(uintptr_t)g,
      (__attribute__((address_space(3))) u32*)(uintptr_t)lds_wave_base, 16, 0, 0);
#else
  uint4 v = *(const uint4*)g;
  *(uint4*)((char*)lds_wave_base + (threadIdx.x & 63) * 16) = v;
#endif
}

// ---------------- fp32 -> bf16 converts ----------------
// grid-stride: 2048 blocks x 256 thr, each iter converts one float4 quad.
__global__ __launch_bounds__(256) void k_cvt(const float* __restrict__ src,
                                             u16* __restrict__ dst, int nq) {
  int stride = gridDim.x * 256;
  for (int i = blockIdx.x * 256 + threadIdx.x; i < nq; i += stride) {
    float4 v = ((const float4*)src)[i];
    ushort4 o;
    o.x = f2bf(v.x); o.y = f2bf(v.y); o.z = f2bf(v.z); o.w = f2bf(v.w);
    ((ushort4*)dst)[i] = o;
  }
}

// merged small converts. nq is in float4 QUADS:
// weights 1024x1024 = 262144 quads; rel tables 16*225*64 = 57600 quads.
__global__ __launch_bounds__(256) void k_cvt7(
    const float* s0, const float* s1, const float* s2, const float* s3,
    const float* s4, const float* s5, const float* s6, u16* d0, u16* d1,
    u16* d2, u16* d3, u16* d4, u16* d5, u16* d6) {
  int seg = blockIdx.y;
  const float* s;
  u16* d;
  int nq;
  switch (seg) {
    case 0: s = s0; d = d0; nq = 262144; break;
    case 1: s = s1; d = d1; nq = 262144; break;
    case 2: s = s2; d = d2; nq = 262144; break;
    case 3: s = s3; d = d3; nq = 262144; break;
    case 4: s = s4; d = d4; nq = 57600; break;
    case 5: s = s5; d = d5; nq = 57600; break;
    default: s = s6; d = d6; nq = 57600; break;
  }
  int stride = gridDim.x * 256;
  for (int i = blockIdx.x * 256 + threadIdx.x; i < nq; i += stride) {
    float4 v = ((const float4*)s)[i];
    ushort4 o;
    o.x = f2bf(v.x); o.y = f2bf(v.y); o.z = f2bf(v.z); o.w = f2bf(v.w);
    ((ushort4*)d)[i] = o;
  }
}

// ================= 256x256 6-phase GEMM core =================
template <int OFF, int KK>
__device__ __forceinline__ void rdAk(const char* lds, const int* abase,
                                     bf16x8 (&f)[4]) {
#pragma unroll
  for (int m = 0; m < 4; m++)
    f[m] = *(const bf16x8*)(lds + abase[KK] + OFF + m * 2048);
}
template <int OFF, int KK>
__device__ __forceinline__ void rdBk(const char* lds, const int* bbase,
                                     bf16x8 (&f)[2]) {
#pragma unroll
  for (int n = 0; n < 2; n++)
    f[n] = *(const bf16x8*)(lds + bbase[KK] + OFF + n * 2048);
}
__device__ __forceinline__ void mq8(f32x4 (&acc)[8][4], const bf16x8 (&af)[4],
                                    const bf16x8 (&bf)[2], int MR, int NC) {
#pragma unroll
  for (int m = 0; m < 4; m++)
#pragma unroll
    for (int n = 0; n < 2; n++)
      acc[MR + m][NC + n] = MFMA16(af[m], bf[n], acc[MR + m][NC + n]);
}
__device__ __forceinline__ void st2(const char* p0, const char* p1, int off,
                                    char* lds, int dst, int woff) {
  g2l16(p0 + off, lds + dst + woff);
  g2l16(p1 + off, lds + dst + 8192 + woff);
}

__device__ __forceinline__ void gemm256_core(const u16* __restrict__ A,
                                             const u16* __restrict__ Bm,
                                             int row0, int col0, char* lds,
                                             f32x4 (&acc)[8][4], int tid) {
  const int lane = tid & 63, w = tid >> 6;
  const int wr = w >> 2, wc = w & 3;
  const int l15 = lane & 15, l4 = lane >> 4;
  const int l7 = l15 & 7;
  int abase[2], bbase[2];
#pragma unroll
  for (int kk = 0; kk < 2; kk++) {
    int swz = ((kk * 4 + l4) ^ l7) << 4;
    abase[kk] = wr * 8192 + l15 * 128 + swz;
    bbase[kk] = 65536 + wc * 4096 + l15 * 128 + swz;
  }
  const int sub0 = tid >> 3, sl0 = tid & 7;
  const int sub1 = (512 + tid) >> 3, sl1 = tid & 7;
  const int woff = w * 1024;
  const char* pa0 = (const char*)A + (size_t)row0 * 2048 +
      (size_t)((sub0 & 63) | ((sub0 & 64) << 1)) * 2048 + (sl0 ^ (sub0 & 7)) * 16;
  const char* pa1 = (const char*)A + (size_t)row0 * 2048 +
      (size_t)((sub1 & 63) | ((sub1 & 64) << 1)) * 2048 + (sl1 ^ (sub1 & 7)) * 16;
  const char* pb0 = (const char*)Bm + (size_t)col0 * 2048 +
      (size_t)((sub0 & 31) | ((sub0 & 0x60) << 1)) * 2048 + (sl0 ^ (sub0 & 7)) * 16;
  const char* pb1 = (const char*)Bm + (size_t)col0 * 2048 +
      (size_t)((sub1 & 31) | ((sub1 & 0x60) << 1)) * 2048 + (sl1 ^ (sub1 & 7)) * 16;

  bf16x8 afA0[4], afA1[4], afC0[4], afC1[4], bfB0[2], bfB1[2];

  st2(pa0, pa1, 0, lds, 0, woff);                    // A0[0]
  st2(pb0, pb1, 0, lds, 65536, woff);                // B0[0]
  st2(pa0, pa1, 131072, lds, 16384, woff);           // A1[0]
  st2(pb0, pb1, 65536, lds, 65536 + 16384, woff);    // B1[0]
  st2(pb0, pb1, 128, lds, 65536 + 32768, woff);      // B0[1]
  st2(pa0, pa1, 131072 + 128, lds, 49152, woff);     // A1[1]
  VMC(0);
  BAR;

  for (int u = 0; u < 7; ++u) {
    const int kB = u * 256;
    // P1[e,q00]: rd A0,B0 ; st A0[o]
    rdAk<0, 0>(lds, abase, afA0); rdBk<0, 0>(lds, bbase, bfB0);
    rdAk<0, 1>(lds, abase, afA1); rdBk<0, 1>(lds, bbase, bfB1);
    st2(pa0, pa1, kB + 128, lds, 32768, woff);
    BAR; LGK(6);
    __builtin_amdgcn_s_setprio(1);
    mq8(acc, afA0, bfB0, 0, 0);
    LGK(0);
    mq8(acc, afA1, bfB1, 0, 0);
    __builtin_amdgcn_s_setprio(0);
    BAR;
    // P2[e,q10]: rd A1 ; st B1[o]
    rdAk<16384, 0>(lds, abase, afC0);
    rdAk<16384, 1>(lds, abase, afC1);
    st2(pb0, pb1, 65536 + kB + 128, lds, 65536 + 49152, woff);
    BAR; LGK(4);
    __builtin_amdgcn_s_setprio(1);
    mq8(acc, afC0, bfB0, 4, 0);
    LGK(0);
    mq8(acc, afC1, bfB1, 4, 0);
    __builtin_amdgcn_s_setprio(0);
    BAR;
    // P3[e,q11+q01]: rd B1 ; st B0[e+2], A1[e+2] ; vm(6)
    rdBk<16384, 0>(lds, bbase, bfB0);
    rdBk<16384, 1>(lds, bbase, bfB1);
    st2(pb0, pb1, kB + 256, lds, 65536, woff);
    st2(pa0, pa1, 131072 + kB + 256, lds, 16384, woff);
    BAR; LGK(2);
    __builtin_amdgcn_s_setprio(1);
    mq8(acc, afC0, bfB0, 4, 2); mq8(acc, afA0, bfB0, 0, 2);
    LGK(0);
    mq8(acc, afC1, bfB1, 4, 2); mq8(acc, afA1, bfB1, 0, 2);
    __builtin_amdgcn_s_setprio(0);
    VMC(6); BAR;
    // P4[o,q00]: rd A0,B0 ; st A0[e+2]
    rdAk<32768, 0>(lds, abase, afA0); rdBk<32768, 0>(lds, bbase, bfB0);
    rdAk<32768, 1>(lds, abase, afA1); rdBk<32768, 1>(lds, bbase, bfB1);
    st2(pa0, pa1, kB + 256, lds, 0, woff);
    BAR; LGK(6);
    __builtin_amdgcn_s_setprio(1);
    mq8(acc, afA0, bfB0, 0, 0);
    LGK(0);
    mq8(acc, afA1, bfB1, 0, 0);
    __builtin_amdgcn_s_setprio(0);
    BAR;
    // P5[o,q10]: rd A1 ; st B1[e+2] ; vm(8)
    rdAk<49152, 0>(lds, abase, afC0);
    rdAk<49152, 1>(lds, abase, afC1);
    st2(pb0, pb1, 65536 + kB + 256, lds, 65536 + 16384, woff);
    BAR; LGK(4);
    __builtin_amdgcn_s_setprio(1);
    mq8(acc, afC0, bfB0, 4, 0);
    LGK(0);
    mq8(acc, afC1, bfB1, 4, 0);
    __builtin_amdgcn_s_setprio(0);
    VMC(8); BAR;
    // P6[o,q11+q01]: rd B1 ; st B0[o+2], A1[o+2] ; vm(4)
    rdBk<49152, 0>(lds, bbase, bfB0);
    rdBk<49152, 1>(lds, bbase, bfB1);
    st2(pb0, pb1, kB + 384, lds, 65536 + 32768, woff);
    st2(pa0, pa1, 131072 + kB + 384, lds, 49152, woff);
    BAR; LGK(2);
    __builtin_amdgcn_s_setprio(1);
    mq8(acc, afC0, bfB0, 4, 2); mq8(acc, afA0, bfB0, 0, 2);
    LGK(0);
    mq8(acc, afC1, bfB1, 4, 2); mq8(acc, afA1, bfB1, 0, 2);
    __builtin_amdgcn_s_setprio(0);
    VMC(4); BAR;
  }
  {  // peeled final iteration (tiles 14,15): stage A0[15]@P1, B1[15]@P2;
     // drains P3 vm(2), P5 vm(0).
    rdAk<0, 0>(lds, abase, afA0); rdBk<0, 0>(lds, bbase, bfB0);
    rdAk<0, 1>(lds, abase, afA1); rdBk<0, 1>(lds, bbase, bfB1);
    st2(pa0, pa1, 1792 + 128, lds, 32768, woff);
    BAR; LGK(6);
    mq8(acc, afA0, bfB0, 0, 0);
    LGK(0);
    mq8(acc, afA1, bfB1, 0, 0);
    BAR;
    rdAk<16384, 0>(lds, abase, afC0);
    rdAk<16384, 1>(lds, abase, afC1);
    st2(pb0, pb1, 65536 + 1792 + 128, lds, 65536 + 49152, woff);
    BAR; LGK(4);
    mq8(acc, afC0, bfB0, 4, 0);
    LGK(0);
    mq8(acc, afC1, bfB1, 4, 0);
    BAR;
    rdBk<16384, 0>(lds, bbase, bfB0);
    rdBk<16384, 1>(lds, bbase, bfB1);
    BAR; LGK(2);
    mq8(acc, afC0, bfB0, 4, 2); mq8(acc, afA0, bfB0, 0, 2);
    LGK(0);
    mq8(acc, afC1, bfB1, 4, 2); mq8(acc, afA1, bfB1, 0, 2);
    VMC(2); BAR;
    rdAk<32768, 0>(lds, abase, afA0); rdBk<32768, 0>(lds, bbase, bfB0);
    rdAk<32768, 1>(lds, abase, afA1); rdBk<32768, 1>(lds, bbase, bfB1);
    BAR; LGK(6);
    mq8(acc, afA0, bfB0, 0, 0);
    LGK(0);
    mq8(acc, afA1, bfB1, 0, 0);
    BAR;
    rdAk<49152, 0>(lds, abase, afC0);
    rdAk<49152, 1>(lds, abase, afC1);
    BAR; LGK(4);
    mq8(acc, afC0, bfB0, 4, 0);
    LGK(0);
    mq8(acc, afC1, bfB1, 4, 0);
    VMC(0); BAR;
    rdBk<49152, 0>(lds, bbase, bfB0);
    rdBk<49152, 1>(lds, bbase, bfB1);
    BAR; LGK(2);
    mq8(acc, afC0, bfB0, 4, 2); mq8(acc, afA0, bfB0, 0, 2);
    LGK(0);
    mq8(acc, afC1, bfB1, 4, 2); mq8(acc, afA1, bfB1, 0, 2);
    BAR;
  }
}

// ---------------- QKV GEMM: [32768x1024] x [3072x1024]^T ----------------
__global__ __launch_bounds__(512, 2) void k_gemm_qkv(
    const u16* __restrict__ A, const u16* __restrict__ Bm,
    const float* __restrict__ bq, const float* __restrict__ bk,
    const float* __restrict__ bv, u16* __restrict__ Qb, u16* __restrict__ Kb,
    u16* __restrict__ Vb) {
  __shared__ char lds[131072];
  const int tid = threadIdx.x;
  const int lane = tid & 63, w = tid >> 6;
  const int wr = w >> 2, wc = w & 3;
  const int l15 = lane & 15, l4 = lane >> 4;
  int f = blockIdx.x;
  int xcd = f & 7, j = f >> 3;
  int band = j / 48, r = j % 48;
  int bcol = r >> 2, brl = r & 3;
  int brow = xcd * 16 + band * 4 + brl;
  const int row0 = brow * 256, col0 = bcol * 256;
  f32x4 acc[8][4] = {};
  gemm256_core(A, Bm, row0, col0, lds, acc, tid);
  // ---- coalesced epilogue via LDS bounce (wave-private 16KB region) ----
  char* eb = lds + w * 16384;
  const int colW = col0 + wc * 64;
  const int sel = colW >> 10, hd = colW & 1023;
  const int h = hd >> 6;
  const float* bp = (sel == 0) ? bq : (sel == 1) ? bk : bv;
  const float* biasW = bp + hd;
  u16* dstW = (sel == 0) ? Qb : (sel == 1) ? Kb : Vb;
#pragma unroll
  for (int rr = 0; rr < 4; rr++) {
#pragma unroll
    for (int mm = 0; mm < 2; mm++) {
      int mf = rr * 2 + mm;
#pragma unroll
      for (int nf = 0; nf < 4; nf++)
#pragma unroll
        for (int jj = 0; jj < 4; jj++) {
          int rowl = mm * 16 + l4 * 4 + jj;
          *(float*)(eb + rowl * 272 + (nf * 16 + l15) * 4) = acc[mf][nf][jj];
        }
    }
    LGK(0);
#pragma unroll
    for (int it = 0; it < 4; it++) {
      int u = it * 64 + lane;
      int rowl = u >> 3, ch = u & 7;
      float4 a0 = *(const float4*)(eb + rowl * 272 + ch * 32);
      float4 a1 = *(const float4*)(eb + rowl * 272 + ch * 32 + 16);
      float4 b0 = *(const float4*)(biasW + ch * 8);
      float4 b1 = *(const float4*)(biasW + ch * 8 + 4);
      uint4 pk;
      pk.x = (u32)f2bf(a0.x + b0.x) | ((u32)f2bf(a0.y + b0.y) << 16);
      pk.y = (u32)f2bf(a0.z + b0.z) | ((u32)f2bf(a0.w + b0.w) << 16);
      pk.z = (u32)f2bf(a1.x + b1.x) | ((u32)f2bf(a1.y + b1.y) << 16);
      pk.w = (u32)f2bf(a1.z + b1.z) | ((u32)f2bf(a1.w + b1.w) << 16);
      int row = row0 + wr * 128 + rr * 32 + rowl;
      int b = row >> 6, t = row & 63;
      *(uint4*)(dstW + ((size_t)(b * 16 + h)) * 4096 + t * 64 + ch * 8) = pk;
    }
    LGK(0);
  }
}

// ---------------- output GEMM: [32768x1024] x [1024x1024]^T + bias -> fp32 --
__global__ __launch_bounds__(512, 2) void k_gemm_out(
    const u16* __restrict__ A, const u16* __restrict__ Bm,
    const float* __restrict__ bo, float* __restrict__ out) {
  __shared__ char lds[131072];
  const int tid = threadIdx.x;
  const int lane = tid & 63, w = tid >> 6;
  const int wr = w >> 2, wc = w & 3;
  const int l15 = lane & 15, l4 = lane >> 4;
  int f = blockIdx.x;
  int xcd = f & 7, j = f >> 3;
  int band = j >> 5, r = j & 31;
  int bcol = r >> 3, brl = r & 7;
  int brow = xcd * 16 + band * 8 + brl;
  const int row0 = brow * 256, col0 = bcol * 256;
  f32x4 acc[8][4] = {};
  gemm256_core(A, Bm, row0, col0, lds, acc, tid);
  char* eb = lds + w * 16384;
  const int colW = col0 + wc * 64;
  const float* biasW = bo + colW;
#pragma unroll
  for (int rr = 0; rr < 4; rr++) {
#pragma unroll
    for (int mm = 0; mm < 2; mm++) {
      int mf = rr * 2 + mm;
#pragma unroll
      for (int nf = 0; nf < 4; nf++)
#pragma unroll
        for (int jj = 0; jj < 4; jj++) {
          int rowl = mm * 16 + l4 * 4 + jj;
          *(float*)(eb + rowl * 272 + (nf * 16 + l15) * 4) = acc[mf][nf][jj];
        }
    }
    LGK(0);
#pragma unroll
    for (int it = 0; it < 8; it++) {
      int u = it * 64 + lane;
      int rowl = u >> 4, ch = u & 15;
      float4 a0 = *(const float4*)(eb + rowl * 272 + ch * 16);
      float4 b0 = *(const float4*)(biasW + ch * 4);
      a0.x += b0.x; a0.y += b0.y; a0.z += b0.z; a0.w += b0.w;
      int row = row0 + wr * 128 + rr * 32 + rowl;
      *(float4*)(out + (size_t)row * 1024 + colW + ch * 4) = a0;
    }
    LGK(0);
  }
}

// ---------------- merged bias kernel: per block does bias1(t=i) + bias2(s=i)
// grid 2048 1D; XCD-h clustering: xcd = f&7 serves h = {2*xcd, 2*xcd+1}.
__global__ __launch_bounds__(256) void k_bias12(
    const u16* __restrict__ Qb, const u16* __restrict__ Kb,
    const u16* __restrict__ relq, const u16* __restrict__ relk,
    const int* __restrict__ relidx, u16* __restrict__ bias1,
    u16* __restrict__ bias2) {
  const int tid = threadIdx.x, lane = tid & 63, w = tid >> 6;
  const int l15 = lane & 15, l4 = lane >> 4;
  int f = blockIdx.x;
  int seq = (f & 7) * 256 + (f >> 3);
  const int h = seq >> 7, bc = (seq >> 6) & 1, i = seq & 63;
  __shared__ char lds[16640];
  char* RK = lds;
  char* RQ = lds + 8192;
  float* T3 = (float*)(lds + 16384);
  char* wb = lds + w * 4096;  // wave-private bounce (reuses RK/RQ space)
  // ---------- part 1: bias1 for t = i ----------
#pragma unroll
  for (int c = 0; c < 2; c++) {
    int ch = c * 256 + tid;
    int sr = ch >> 3, sl = (ch & 7) ^ (sr & 7);
    int ri = relidx[i * 64 + sr];
    size_t so = ((size_t)h * 225 + ri) * 64 + sl * 8;
    g2l16(relk + so, RK + c * 4096 + w * 1024);
    g2l16(relq + so, RQ + c * 4096 + w * 1024);
  }
  __syncthreads();
  if (tid < 64) {
    int sr = tid;
    float sum = 0.f;
#pragma unroll
    for (int sl = 0; sl < 8; sl++) {
      int o = sr * 128 + ((sl ^ (sr & 7)) << 4);
      bf16x8 aq = *(const bf16x8*)(RQ + o);
      bf16x8 ak = *(const bf16x8*)(RK + o);
#pragma unroll
      for (int j = 0; j < 8; j++) sum += (float)aq[j] * (float)ak[j];
    }
    T3[sr] = sum;
  }
  {
    bf16x8 bfr[4][2];
#pragma unroll
    for (int n = 0; n < 4; n++)
#pragma unroll
      for (int kh = 0; kh < 2; kh++) {
        int r = n * 16 + l15;
        int sl = ((kh << 2) + l4) ^ (r & 7);
        bfr[n][kh] = *(const bf16x8*)(RK + r * 128 + sl * 16);
      }
    __syncthreads();
    f32x4 acc[4][4] = {};
#pragma unroll
    for (int m = 0; m < 4; m++) {
      int bb = bc * 256 + w * 64 + m * 16 + l15;
      const u16* ap = Qb + ((size_t)(bb * 16 + h)) * 4096 + i * 64 + l4 * 8;
      bf16x8 a0 = *(const bf16x8*)ap;
      bf16x8 a1 = *(const bf16x8*)(ap + 32);
#pragma unroll
      for (int n = 0; n < 4; n++) {
        acc[m][n] = MFMA16(a0, bfr[n][0], acc[m][n]);
        acc[m][n] = MFMA16(a1, bfr[n][1], acc[m][n]);
      }
    }
    __syncthreads();  // all waves done reading RK fragments before bounce
#pragma unroll
    for (int m = 0; m < 4; m++) {
#pragma unroll
      for (int n = 0; n < 4; n++)
#pragma unroll
        for (int j = 0; j < 4; j++)
          *(float*)(wb + (l4 * 4 + j) * 256 + (n * 16 + l15) * 4) =
              acc[m][n][j];
      LGK(0);
#pragma unroll
      for (int it = 0; it < 4; it++) {
        int u = it * 64 + lane;
        int row = u >> 4, colf = (u & 15) * 4;
        float4 a0 = *(const float4*)(wb + row * 256 + colf * 4);
        float4 t3 = *(const float4*)(T3 + colf);
        uint2 pk;
        pk.x = (u32)f2bf(a0.x + t3.x) | ((u32)f2bf(a0.y + t3.y) << 16);
        pk.y = (u32)f2bf(a0.z + t3.z) | ((u32)f2bf(a0.w + t3.w) << 16);
        int bb = bc * 256 + w * 64 + m * 16 + row;
        *(uint2*)(bias1 + ((size_t)(bb * 16 + h)) * 4096 + i * 64 + colf) = pk;
      }
      LGK(0);
    }
  }
  __syncthreads();
  // ---------- part 2: bias2 for s = i (gather relq at idx[tq, i]) ----------
#pragma unroll
  for (int c = 0; c < 2; c++) {
    int ch = c * 256 + tid;
    int tq = ch >> 3, sl = (ch & 7) ^ (tq & 7);
    int ri = relidx[tq * 64 + i];
    g2l16(relq + ((size_t)h * 225 + ri) * 64 + sl * 8,
          RK + c * 4096 + w * 1024);
  }
  __syncthreads();
  {
    bf16x8 bfr[4][2];
#pragma unroll
    for (int n = 0; n < 4; n++)
#pragma unroll
      for (int kh = 0; kh < 2; kh++) {
        int r = n * 16 + l15;
        int sl = ((kh << 2) + l4) ^ (r & 7);
        bfr[n][kh] = *(const bf16x8*)(RK + r * 128 + sl * 16);
      }
    f32x4 acc[4][4] = {};
#pragma unroll
    for (int m = 0; m < 4; m++) {
      int bb = bc * 256 + w * 64 + m * 16 + l15;
      const u16* ap = Kb + ((size_t)(bb * 16 + h)) * 4096 + i * 64 + l4 * 8;
      bf16x8 a0 = *(const bf16x8*)ap;
      bf16x8 a1 = *(const bf16x8*)(ap + 32);
#pragma unroll
      for (int n = 0; n < 4; n++) {
        acc[m][n] = MFMA16(a0, bfr[n][0], acc[m][n]);
        acc[m][n] = MFMA16(a1, bfr[n][1], acc[m][n]);
      }
    }
    __syncthreads();  // all waves done reading RK fragments before bounce
#pragma unroll
    for (int m = 0; m < 4; m++) {
#pragma unroll
      for (int n = 0; n < 4; n++)
#pragma unroll
        for (int j = 0; j < 4; j++)
          *(float*)(wb + (l4 * 4 + j) * 256 + (n * 16 + l15) * 4) =
              acc[m][n][j];
      LGK(0);
#pragma unroll
      for (int it = 0; it < 4; it++) {
        int u = it * 64 + lane;
        int row = u >> 4, colf = (u & 15) * 4;
        float4 a0 = *(const float4*)(wb + row * 256 + colf * 4);
        uint2 pk;
        pk.x = (u32)f2bf(a0.x) | ((u32)f2bf(a0.y) << 16);
        pk.y = (u32)f2bf(a0.z) | ((u32)f2bf(a0.w) << 16);
        int bb = bc * 256 + w * 64 + m * 16 + row;
        *(uint2*)(bias2 + ((size_t)(bb * 16 + h)) * 4096 + i * 64 + colf) = pk;
      }
      LGK(0);
    }
  }
}

// ---------------- attention per (b,h): S=QK^T + b1 + b2^T, softmax, P, PV ----
__global__ __launch_bounds__(256) void k_attn(
    const u16* __restrict__ Qb, const u16* __restrict__ Kb,
    const u16* __restrict__ Vb, const u16* __restrict__ b1g,
    const u16* __restrict__ b2g, u16* __restrict__ Pg,
    u16* __restrict__ aout) {
  const int tid = threadIdx.x, lane = tid & 63, w = tid >> 6;
  const int l15 = lane & 15, l4 = lane >> 4;
  const int b = blockIdx.x, h = blockIdx.y;
  __shared__ char lds[49152];
  char* Qt = lds;
  char* Kt = lds + 8192;
  char* Vt = lds + 16384;
  char* B1 = lds + 24576;
  char* B2 = lds + 32768;
  char* Pt = lds + 40960;
  const size_t base = ((size_t)(b * 16 + h)) * 4096;
#pragma unroll
  for (int c = 0; c < 2; c++) {
    int ch = c * 256 + tid;
    int r = ch >> 3, sl = (ch & 7) ^ (r & 7);
    size_t so = base + r * 64 + sl * 8;
    int dst = c * 4096 + w * 1024;
    g2l16(Qb + so, Qt + dst);
    g2l16(Kb + so, Kt + dst);
    g2l16(Vb + so, Vt + dst);
    g2l16(b1g + so, B1 + dst);
    g2l16(b2g + so, B2 + dst);
  }
  __syncthreads();
  f32x4 acc[4] = {};
  bf16x8 qf[2];
  {
    int r = w * 16 + l15;
#pragma unroll
    for (int kh = 0; kh < 2; kh++) {
      int sl = ((kh << 2) + l4) ^ (r & 7);
      qf[kh] = *(const bf16x8*)(Qt + r * 128 + sl * 16);
    }
  }
#pragma unroll
  for (int n = 0; n < 4; n++) {
    int r = n * 16 + l15;
#pragma unroll
    for (int kh = 0; kh < 2; kh++) {
      int sl = ((kh << 2) + l4) ^ (r & 7);
      bf16x8 kf = *(const bf16x8*)(Kt + r * 128 + sl * 16);
      acc[n] = MFMA16(qf[kh], kf, acc[n]);
    }
  }
  const int t0 = w * 16 + l4 * 4;
#pragma unroll
  for (int j = 0; j < 4; j++) {
    int t_ = t0 + j;
    float lv[4];
#pragma unroll
    for (int n = 0; n < 4; n++) {
      int s_ = n * 16 + l15;
      float x = acc[n][j];
      x += bf2f(*(const u16*)(B1 + t_ * 128 + ((s_ * 2) ^ ((t_ & 7) << 4))));
      x += bf2f(*(const u16*)(B2 + s_ * 128 + ((t_ * 2) ^ ((s_ & 7) << 4))));
      lv[n] = x * 0.125f;
    }
    float mx = fmaxf(fmaxf(lv[0], lv[1]), fmaxf(lv[2], lv[3]));
#pragma unroll
    for (int d = 1; d < 16; d <<= 1) mx = fmaxf(mx, __shfl_xor(mx, d, 64));
    float e0 = __expf(lv[0] - mx), e1 = __expf(lv[1] - mx);
    float e2 = __expf(lv[2] - mx), e3 = __expf(lv[3] - mx);
    float sum = e0 + e1 + e2 + e3;
#pragma unroll
    for (int d = 1; d < 16; d <<= 1) sum += __shfl_xor(sum, d, 64);
    float inv = 1.0f / sum;
    float pe[4] = {e0 * inv, e1 * inv, e2 * inv, e3 * inv};
#pragma unroll
    for (int n = 0; n < 4; n++) {
      int s_ = n * 16 + l15;
      *(u16*)(Pt + t_ * 128 + ((s_ * 2) ^ ((t_ & 7) << 4))) = f2bf(pe[n]);
    }
  }
  __syncthreads();
#pragma unroll
  for (int c = 0; c < 2; c++) {
    int ch = c * 256 + tid;
    int r = ch >> 3, sl = ch & 7;
    uint4 v = *(const uint4*)(Pt + r * 128 + ((sl ^ (r & 7)) << 4));
    *((uint4*)(Pg + base) + ch) = v;
  }
  f32x4 acc2[4] = {};
  bf16x8 pf[2];
  {
    int r = w * 16 + l15;
#pragma unroll
    for (int kh = 0; kh < 2; kh++) {
      int sl = ((kh << 2) + l4) ^ (r & 7);
      pf[kh] = *(const bf16x8*)(Pt + r * 128 + sl * 16);
    }
  }
#pragma unroll
  for (int n = 0; n < 4; n++) {
#pragma unroll
    for (int kh = 0; kh < 2; kh++) {
      bf16x8 tmp;
#pragma unroll
      for (int j = 0; j < 8; j++) {
        int s_ = (kh << 5) + (l4 << 3) + j;
        int d_ = n * 16 + l15;
        u16 uu = *(const u16*)(Vt + s_ * 128 + ((d_ * 2) ^ ((s_ & 7) << 4)));
        tmp[j] = __builtin_bit_cast(__bf16, uu);
      }
      acc2[n] = MFMA16(pf[kh], tmp, acc2[n]);
    }
  }
#pragma unroll
  for (int n = 0; n < 4; n++)
#pragma unroll
    for (int j = 0; j < 4; j++) {
      int t_ = t0 + j, d_ = n * 16 + l15;
      aout[((size_t)(b * 64 + t_)) * 1024 + h * 64 + d_] = f2bf(acc2[n][j]);
    }
}

// ---------------- out_relv: aout[b,t,h,d] += sum_s P[b,s]*rel_v[idx[t,s],d]
// grid 2048 1D with XCD-h clustering (same decode as k_bias12).
__global__ __launch_bounds__(256) void k_relv(
    const u16* __restrict__ Pg, const u16* __restrict__ relv,
    const int* __restrict__ relidx, u16* __restrict__ aout) {
  const int tid = threadIdx.x, lane = tid & 63, w = tid >> 6;
  const int l15 = lane & 15, l4 = lane >> 4;
  int f = blockIdx.x;
  int seq = (f & 7) * 256 + (f >> 3);
  const int h = seq >> 7, bc = (seq >> 6) & 1, t = seq & 63;
  __shared__ char lds[8192];
#pragma unroll
  for (int c = 0; c < 2; c++) {
    int ch = c * 256 + tid;
    int sr = ch >> 3, sl = (ch & 7) ^ (sr & 7);
    int ri = relidx[t * 64 + sr];
    g2l16(relv + ((size_t)h * 225 + ri) * 64 + sl * 8,
          lds + c * 4096 + w * 1024);
  }
  __syncthreads();
  bf16x8 bfr[4][2];
#pragma unroll
  for (int n = 0; n < 4; n++)
#pragma unroll
    for (int kh = 0; kh < 2; kh++) {
      bf16x8 tmp;
#pragma unroll
      for (int j = 0; j < 8; j++) {
        int s_ = (kh << 5) + (l4 << 3) + j;
        int d_ = n * 16 + l15;
        u16 u = *(const u16*)(lds + s_ * 128 + ((d_ * 2) ^ ((s_ & 7) << 4)));
        tmp[j] = __builtin_bit_cast(__bf16, u);
      }
      bfr[n][kh] = tmp;
    }
  f32x4 acc[4][4] = {};
#pragma unroll
  for (int m = 0; m < 4; m++) {
    int bb = bc * 256 + w * 64 + m * 16 + l15;
    const u16* ap = Pg + ((size_t)(bb * 16 + h)) * 4096 + t * 64 + l4 * 8;
    bf16x8 a0 = *(const bf16x8*)ap;
    bf16x8 a1 = *(const bf16x8*)(ap + 32);
#pragma unroll
    for (int n = 0; n < 4; n++) {
      acc[m][n] = MFMA16(a0, bfr[n][0], acc[m][n]);
      acc[m][n] = MFMA16(a1, bfr[n][1], acc[m][n]);
    }
  }
#pragma unroll
  for (int m = 0; m < 4; m++)
#pragma unroll
    for (int n = 0; n < 4; n++)
#pragma unroll
      for (int j = 0; j < 4; j++) {
        int bb = bc * 256 + w * 64 + m * 16 + l4 * 4 + j;
        int d_ = n * 16 + l15;
        size_t o = ((size_t)(bb * 64 + t)) * 1024 + h * 64 + d_;
        aout[o] = f2bf(bf2f(aout[o]) + acc[m][n][j]);
      }
}

extern "C" void kernel_launch(void* const* d_in, const int* in_sizes, int n_in,
                              void* d_out, int out_size, void* d_ws,
                              size_t ws_size, hipStream_t stream) {
  const float* x = (const float*)d_in[0];
  const float* Wq = (const float*)d_in[1];
  const float* bq = (const float*)d_in[2];
  const float* Wk = (const float*)d_in[3];
  const float* bk = (const float*)d_in[4];
  const float* Wv = (const float*)d_in[5];
  const float* bv = (const float*)d_in[6];
  const float* Wo = (const float*)d_in[7];
  const float* bo = (const float*)d_in[8];
  const float* rq = (const float*)d_in[9];
  const float* rk = (const float*)d_in[10];
  const float* rv = (const float*)d_in[11];
  const int* ridx = (const int*)d_in[12];
  float* out = (float*)d_out;

  char* ws = (char*)d_ws;
  const size_t MB = 1ull << 20;
  u16* xb = (u16*)(ws + 0);  // reused as P after k_gemm_qkv consumes it
  u16* Qb = (u16*)(ws + 64 * MB);
  u16* Kb = (u16*)(ws + 128 * MB);
  u16* Vb = (u16*)(ws + 192 * MB);
  u16* b1 = (u16*)(ws + 256 * MB);
  u16* b2 = (u16*)(ws + 320 * MB);
  u16* aout = (u16*)(ws + 384 * MB);
  u16* wqkv = (u16*)(ws + 448 * MB);
  u16* wo = (u16*)(ws + 454 * MB);
  u16* relq = (u16*)(ws + 456 * MB);
  u16* relk = (u16*)(ws + 457 * MB);
  u16* relv = (u16*)(ws + 458 * MB);
  u16* Pg = xb;

  k_cvt<<<2048, 256, 0, stream>>>(x, xb, 8388608);
  k_cvt7<<<dim3(1024, 7), 256, 0, stream>>>(
      Wq, Wk, Wv, Wo, rq, rk, rv, wqkv, wqkv + 1048576, wqkv + 2097152, wo,
      relq, relk, relv);

  k_gemm_qkv<<<1536, 512, 0, stream>>>(xb, wqkv, bq, bk, bv, Qb, Kb, Vb);
  k_bias12<<<2048, 256, 0, stream>>>(Qb, Kb, relq, relk, ridx, b1, b2);
  k_attn<<<dim3(512, 16), 256, 0, stream>>>(Qb, Kb, Vb, b1, b2, Pg, aout);
  k_relv<<<2048, 256, 0, stream>>>(Pg, relv, ridx, aout);
  k_gemm_out<<<512, 512, 0, stream>>>(aout, wo, bo, out);
}

// Round 14
// 520.559 us; speedup vs baseline: 1.0078x; 1.0078x over previous
//
#include <hip/hip_runtime.h>
#include <cstdint>

// ChessRelativeTransformer on MI355X (gfx950), bf16 MFMA pipeline.
// B=512 T=64 H=16 DH=64 D=1024 NUM_REL=225 scale=0.125
// R14: revert to exact R12 configuration (best measured: 521.2us).
//      R13's grid-stride k_cvt was a small regression; per-quad k_cvt
//      restored. Session summary: 673 -> 521us. qkv at 41% MfmaUtil is
//      the 6-phase structure's ceiling (7 levers tested null); non-GEMM
//      kernels near HBM floors.

typedef unsigned short u16;
typedef unsigned int u32;
typedef __bf16 bf16x8 __attribute__((ext_vector_type(8)));
typedef float f32x4 __attribute__((ext_vector_type(4)));

#define MFMA16(a, b, c) __builtin_amdgcn_mfma_f32_16x16x32_bf16(a, b, c, 0, 0, 0)
#define BAR __builtin_amdgcn_s_barrier()
#define LGK(n) asm volatile("s_waitcnt lgkmcnt(" #n ")" ::: "memory")
#define VMC(n) asm volatile("s_waitcnt vmcnt(" #n ")" ::: "memory")

__device__ __forceinline__ u16 f2bf(float f) {
  u32 u = __builtin_bit_cast(u32, f);
  u = (u + 0x7FFFu + ((u >> 16) & 1u)) >> 16;
  return (u16)u;
}
__device__ __forceinline__ float bf2f(u16 h) {
  return __builtin_bit_cast(float, ((u32)h) << 16);
}

__device__ __forceinline__ void g2l16(const void* g, void* lds_wave_base) {
#if __has_builtin(__builtin_amdgcn_global_load_lds)
  __builtin_amdgcn_global_load_lds(
      (const __attribute__((address_space(1))) u32*)(uintptr_t)g,
      (__attribute__((address_space(3))) u32*)(uintptr_t)lds_wave_base, 16, 0, 0);
#else
  uint4 v = *(const uint4*)g;
  *(uint4*)((char*)lds_wave_base + (threadIdx.x & 63) * 16) = v;
#endif
}

// ---------------- fp32 -> bf16 converts ----------------
__global__ __launch_bounds__(256) void k_cvt(const float* __restrict__ src,
                                             u16* __restrict__ dst, int nq) {
  int i = blockIdx.x * 256 + threadIdx.x;
  if (i >= nq) return;
  float4 v = ((const float4*)src)[i];
  ushort4 o;
  o.x = f2bf(v.x); o.y = f2bf(v.y); o.z = f2bf(v.z); o.w = f2bf(v.w);
  ((ushort4*)dst)[i] = o;
}

// merged small converts. nq is in float4 QUADS:
// weights 1024x1024 = 262144 quads; rel tables 16*225*64 = 57600 quads.
__global__ __launch_bounds__(256) void k_cvt7(
    const float* s0, const float* s1, const float* s2, const float* s3,
    const float* s4, const float* s5, const float* s6, u16* d0, u16* d1,
    u16* d2, u16* d3, u16* d4, u16* d5, u16* d6) {
  int seg = blockIdx.y;
  const float* s;
  u16* d;
  int nq;
  switch (seg) {
    case 0: s = s0; d = d0; nq = 262144; break;
    case 1: s = s1; d = d1; nq = 262144; break;
    case 2: s = s2; d = d2; nq = 262144; break;
    case 3: s = s3; d = d3; nq = 262144; break;
    case 4: s = s4; d = d4; nq = 57600; break;
    case 5: s = s5; d = d5; nq = 57600; break;
    default: s = s6; d = d6; nq = 57600; break;
  }
  int i = blockIdx.x * 256 + threadIdx.x;
  if (i >= nq) return;
  float4 v = ((const float4*)s)[i];
  ushort4 o;
  o.x = f2bf(v.x); o.y = f2bf(v.y); o.z = f2bf(v.z); o.w = f2bf(v.w);
  ((ushort4*)d)[i] = o;
}

// ================= 256x256 6-phase GEMM core =================
template <int OFF, int KK>
__device__ __forceinline__ void rdAk(const char* lds, const int* abase,
                                     bf16x8 (&f)[4]) {
#pragma unroll
  for (int m = 0; m < 4; m++)
    f[m] = *(const bf16x8*)(lds + abase[KK] + OFF + m * 2048);
}
template <int OFF, int KK>
__device__ __forceinline__ void rdBk(const char* lds, const int* bbase,
                                     bf16x8 (&f)[2]) {
#pragma unroll
  for (int n = 0; n < 2; n++)
    f[n] = *(const bf16x8*)(lds + bbase[KK] + OFF + n * 2048);
}
__device__ __forceinline__ void mq8(f32x4 (&acc)[8][4], const bf16x8 (&af)[4],
                                    const bf16x8 (&bf)[2], int MR, int NC) {
#pragma unroll
  for (int m = 0; m < 4; m++)
#pragma unroll
    for (int n = 0; n < 2; n++)
      acc[MR + m][NC + n] = MFMA16(af[m], bf[n], acc[MR + m][NC + n]);
}
__device__ __forceinline__ void st2(const char* p0, const char* p1, int off,
                                    char* lds, int dst, int woff) {
  g2l16(p0 + off, lds + dst + woff);
  g2l16(p1 + off, lds + dst + 8192 + woff);
}

__device__ __forceinline__ void gemm256_core(const u16* __restrict__ A,
                                             const u16* __restrict__ Bm,
                                             int row0, int col0, char* lds,
                                             f32x4 (&acc)[8][4], int tid) {
  const int lane = tid & 63, w = tid >> 6;
  const int wr = w >> 2, wc = w & 3;
  const int l15 = lane & 15, l4 = lane >> 4;
  const int l7 = l15 & 7;
  int abase[2], bbase[2];
#pragma unroll
  for (int kk = 0; kk < 2; kk++) {
    int swz = ((kk * 4 + l4) ^ l7) << 4;
    abase[kk] = wr * 8192 + l15 * 128 + swz;
    bbase[kk] = 65536 + wc * 4096 + l15 * 128 + swz;
  }
  const int sub0 = tid >> 3, sl0 = tid & 7;
  const int sub1 = (512 + tid) >> 3, sl1 = tid & 7;
  const int woff = w * 1024;
  const char* pa0 = (const char*)A + (size_t)row0 * 2048 +
      (size_t)((sub0 & 63) | ((sub0 & 64) << 1)) * 2048 + (sl0 ^ (sub0 & 7)) * 16;
  const char* pa1 = (const char*)A + (size_t)row0 * 2048 +
      (size_t)((sub1 & 63) | ((sub1 & 64) << 1)) * 2048 + (sl1 ^ (sub1 & 7)) * 16;
  const char* pb0 = (const char*)Bm + (size_t)col0 * 2048 +
      (size_t)((sub0 & 31) | ((sub0 & 0x60) << 1)) * 2048 + (sl0 ^ (sub0 & 7)) * 16;
  const char* pb1 = (const char*)Bm + (size_t)col0 * 2048 +
      (size_t)((sub1 & 31) | ((sub1 & 0x60) << 1)) * 2048 + (sl1 ^ (sub1 & 7)) * 16;

  bf16x8 afA0[4], afA1[4], afC0[4], afC1[4], bfB0[2], bfB1[2];

  st2(pa0, pa1, 0, lds, 0, woff);                    // A0[0]
  st2(pb0, pb1, 0, lds, 65536, woff);                // B0[0]
  st2(pa0, pa1, 131072, lds, 16384, woff);           // A1[0]
  st2(pb0, pb1, 65536, lds, 65536 + 16384, woff);    // B1[0]
  st2(pb0, pb1, 128, lds, 65536 + 32768, woff);      // B0[1]
  st2(pa0, pa1, 131072 + 128, lds, 49152, woff);     // A1[1]
  VMC(0);
  BAR;

  for (int u = 0; u < 7; ++u) {
    const int kB = u * 256;
    // P1[e,q00]: rd A0,B0 ; st A0[o]
    rdAk<0, 0>(lds, abase, afA0); rdBk<0, 0>(lds, bbase, bfB0);
    rdAk<0, 1>(lds, abase, afA1); rdBk<0, 1>(lds, bbase, bfB1);
    st2(pa0, pa1, kB + 128, lds, 32768, woff);
    BAR; LGK(6);
    __builtin_amdgcn_s_setprio(1);
    mq8(acc, afA0, bfB0, 0, 0);
    LGK(0);
    mq8(acc, afA1, bfB1, 0, 0);
    __builtin_amdgcn_s_setprio(0);
    BAR;
    // P2[e,q10]: rd A1 ; st B1[o]
    rdAk<16384, 0>(lds, abase, afC0);
    rdAk<16384, 1>(lds, abase, afC1);
    st2(pb0, pb1, 65536 + kB + 128, lds, 65536 + 49152, woff);
    BAR; LGK(4);
    __builtin_amdgcn_s_setprio(1);
    mq8(acc, afC0, bfB0, 4, 0);
    LGK(0);
    mq8(acc, afC1, bfB1, 4, 0);
    __builtin_amdgcn_s_setprio(0);
    BAR;
    // P3[e,q11+q01]: rd B1 ; st B0[e+2], A1[e+2] ; vm(6)
    rdBk<16384, 0>(lds, bbase, bfB0);
    rdBk<16384, 1>(lds, bbase, bfB1);
    st2(pb0, pb1, kB + 256, lds, 65536, woff);
    st2(pa0, pa1, 131072 + kB + 256, lds, 16384, woff);
    BAR; LGK(2);
    __builtin_amdgcn_s_setprio(1);
    mq8(acc, afC0, bfB0, 4, 2); mq8(acc, afA0, bfB0, 0, 2);
    LGK(0);
    mq8(acc, afC1, bfB1, 4, 2); mq8(acc, afA1, bfB1, 0, 2);
    __builtin_amdgcn_s_setprio(0);
    VMC(6); BAR;
    // P4[o,q00]: rd A0,B0 ; st A0[e+2]
    rdAk<32768, 0>(lds, abase, afA0); rdBk<32768, 0>(lds, bbase, bfB0);
    rdAk<32768, 1>(lds, abase, afA1); rdBk<32768, 1>(lds, bbase, bfB1);
    st2(pa0, pa1, kB + 256, lds, 0, woff);
    BAR; LGK(6);
    __builtin_amdgcn_s_setprio(1);
    mq8(acc, afA0, bfB0, 0, 0);
    LGK(0);
    mq8(acc, afA1, bfB1, 0, 0);
    __builtin_amdgcn_s_setprio(0);
    BAR;
    // P5[o,q10]: rd A1 ; st B1[e+2] ; vm(8)
    rdAk<49152, 0>(lds, abase, afC0);
    rdAk<49152, 1>(lds, abase, afC1);
    st2(pb0, pb1, 65536 + kB + 256, lds, 65536 + 16384, woff);
    BAR; LGK(4);
    __builtin_amdgcn_s_setprio(1);
    mq8(acc, afC0, bfB0, 4, 0);
    LGK(0);
    mq8(acc, afC1, bfB1, 4, 0);
    __builtin_amdgcn_s_setprio(0);
    VMC(8); BAR;
    // P6[o,q11+q01]: rd B1 ; st B0[o+2], A1[o+2] ; vm(4)
    rdBk<49152, 0>(lds, bbase, bfB0);
    rdBk<49152, 1>(lds, bbase, bfB1);
    st2(pb0, pb1, kB + 384, lds, 65536 + 32768, woff);
    st2(pa0, pa1, 131072 + kB + 384, lds, 49152, woff);
    BAR; LGK(2);
    __builtin_amdgcn_s_setprio(1);
    mq8(acc, afC0, bfB0, 4, 2); mq8(acc, afA0, bfB0, 0, 2);
    LGK(0);
    mq8(acc, afC1, bfB1, 4, 2); mq8(acc, afA1, bfB1, 0, 2);
    __builtin_amdgcn_s_setprio(0);
    VMC(4); BAR;
  }
  {  // peeled final iteration (tiles 14,15): stage A0[15]@P1, B1[15]@P2;
     // drains P3 vm(2), P5 vm(0).
    rdAk<0, 0>(lds, abase, afA0); rdBk<0, 0>(lds, bbase, bfB0);
    rdAk<0, 1>(lds, abase, afA1); rdBk<0, 1>(lds, bbase, bfB1);
    st2(pa0, pa1, 1792 + 128, lds, 32768, woff);
    BAR; LGK(6);
    mq8(acc, afA0, bfB0, 0, 0);
    LGK(0);
    mq8(acc, afA1, bfB1, 0, 0);
    BAR;
    rdAk<16384, 0>(lds, abase, afC0);
    rdAk<16384, 1>(lds, abase, afC1);
    st2(pb0, pb1, 65536 + 1792 + 128, lds, 65536 + 49152, woff);
    BAR; LGK(4);
    mq8(acc, afC0, bfB0, 4, 0);
    LGK(0);
    mq8(acc, afC1, bfB1, 4, 0);
    BAR;
    rdBk<16384, 0>(lds, bbase, bfB0);
    rdBk<16384, 1>(lds, bbase, bfB1);
    BAR; LGK(2);
    mq8(acc, afC0, bfB0, 4, 2); mq8(acc, afA0, bfB0, 0, 2);
    LGK(0);
    mq8(acc, afC1, bfB1, 4, 2); mq8(acc, afA1, bfB1, 0, 2);
    VMC(2); BAR;
    rdAk<32768, 0>(lds, abase, afA0); rdBk<32768, 0>(lds, bbase, bfB0);
    rdAk<32768, 1>(lds, abase, afA1); rdBk<32768, 1>(lds, bbase, bfB1);
    BAR; LGK(6);
    mq8(acc, afA0, bfB0, 0, 0);
    LGK(0);
    mq8(acc, afA1, bfB1, 0, 0);
    BAR;
    rdAk<49152, 0>(lds, abase, afC0);
    rdAk<49152, 1>(lds, abase, afC1);
    BAR; LGK(4);
    mq8(acc, afC0, bfB0, 4, 0);
    LGK(0);
    mq8(acc, afC1, bfB1, 4, 0);
    VMC(0); BAR;
    rdBk<49152, 0>(lds, bbase, bfB0);
    rdBk<49152, 1>(lds, bbase, bfB1);
    BAR; LGK(2);
    mq8(acc, afC0, bfB0, 4, 2); mq8(acc, afA0, bfB0, 0, 2);
    LGK(0);
    mq8(acc, afC1, bfB1, 4, 2); mq8(acc, afA1, bfB1, 0, 2);
    BAR;
  }
}

// ---------------- QKV GEMM: [32768x1024] x [3072x1024]^T ----------------
__global__ __launch_bounds__(512, 2) void k_gemm_qkv(
    const u16* __restrict__ A, const u16* __restrict__ Bm,
    const float* __restrict__ bq, const float* __restrict__ bk,
    const float* __restrict__ bv, u16* __restrict__ Qb, u16* __restrict__ Kb,
    u16* __restrict__ Vb) {
  __shared__ char lds[131072];
  const int tid = threadIdx.x;
  const int lane = tid & 63, w = tid >> 6;
  const int wr = w >> 2, wc = w & 3;
  const int l15 = lane & 15, l4 = lane >> 4;
  int f = blockIdx.x;
  int xcd = f & 7, j = f >> 3;
  int band = j / 48, r = j % 48;
  int bcol = r >> 2, brl = r & 3;
  int brow = xcd * 16 + band * 4 + brl;
  const int row0 = brow * 256, col0 = bcol * 256;
  f32x4 acc[8][4] = {};
  gemm256_core(A, Bm, row0, col0, lds, acc, tid);
  // ---- coalesced epilogue via LDS bounce (wave-private 16KB region) ----
  char* eb = lds + w * 16384;
  const int colW = col0 + wc * 64;
  const int sel = colW >> 10, hd = colW & 1023;
  const int h = hd >> 6;
  const float* bp = (sel == 0) ? bq : (sel == 1) ? bk : bv;
  const float* biasW = bp + hd;
  u16* dstW = (sel == 0) ? Qb : (sel == 1) ? Kb : Vb;
#pragma unroll
  for (int rr = 0; rr < 4; rr++) {
#pragma unroll
    for (int mm = 0; mm < 2; mm++) {
      int mf = rr * 2 + mm;
#pragma unroll
      for (int nf = 0; nf < 4; nf++)
#pragma unroll
        for (int jj = 0; jj < 4; jj++) {
          int rowl = mm * 16 + l4 * 4 + jj;
          *(float*)(eb + rowl * 272 + (nf * 16 + l15) * 4) = acc[mf][nf][jj];
        }
    }
    LGK(0);
#pragma unroll
    for (int it = 0; it < 4; it++) {
      int u = it * 64 + lane;
      int rowl = u >> 3, ch = u & 7;
      float4 a0 = *(const float4*)(eb + rowl * 272 + ch * 32);
      float4 a1 = *(const float4*)(eb + rowl * 272 + ch * 32 + 16);
      float4 b0 = *(const float4*)(biasW + ch * 8);
      float4 b1 = *(const float4*)(biasW + ch * 8 + 4);
      uint4 pk;
      pk.x = (u32)f2bf(a0.x + b0.x) | ((u32)f2bf(a0.y + b0.y) << 16);
      pk.y = (u32)f2bf(a0.z + b0.z) | ((u32)f2bf(a0.w + b0.w) << 16);
      pk.z = (u32)f2bf(a1.x + b1.x) | ((u32)f2bf(a1.y + b1.y) << 16);
      pk.w = (u32)f2bf(a1.z + b1.z) | ((u32)f2bf(a1.w + b1.w) << 16);
      int row = row0 + wr * 128 + rr * 32 + rowl;
      int b = row >> 6, t = row & 63;
      *(uint4*)(dstW + ((size_t)(b * 16 + h)) * 4096 + t * 64 + ch * 8) = pk;
    }
    LGK(0);
  }
}

// ---------------- output GEMM: [32768x1024] x [1024x1024]^T + bias -> fp32 --
__global__ __launch_bounds__(512, 2) void k_gemm_out(
    const u16* __restrict__ A, const u16* __restrict__ Bm,
    const float* __restrict__ bo, float* __restrict__ out) {
  __shared__ char lds[131072];
  const int tid = threadIdx.x;
  const int lane = tid & 63, w = tid >> 6;
  const int wr = w >> 2, wc = w & 3;
  const int l15 = lane & 15, l4 = lane >> 4;
  int f = blockIdx.x;
  int xcd = f & 7, j = f >> 3;
  int band = j >> 5, r = j & 31;
  int bcol = r >> 3, brl = r & 7;
  int brow = xcd * 16 + band * 8 + brl;
  const int row0 = brow * 256, col0 = bcol * 256;
  f32x4 acc[8][4] = {};
  gemm256_core(A, Bm, row0, col0, lds, acc, tid);
  char* eb = lds + w * 16384;
  const int colW = col0 + wc * 64;
  const float* biasW = bo + colW;
#pragma unroll
  for (int rr = 0; rr < 4; rr++) {
#pragma unroll
    for (int mm = 0; mm < 2; mm++) {
      int mf = rr * 2 + mm;
#pragma unroll
      for (int nf = 0; nf < 4; nf++)
#pragma unroll
        for (int jj = 0; jj < 4; jj++) {
          int rowl = mm * 16 + l4 * 4 + jj;
          *(float*)(eb + rowl * 272 + (nf * 16 + l15) * 4) = acc[mf][nf][jj];
        }
    }
    LGK(0);
#pragma unroll
    for (int it = 0; it < 8; it++) {
      int u = it * 64 + lane;
      int rowl = u >> 4, ch = u & 15;
      float4 a0 = *(const float4*)(eb + rowl * 272 + ch * 16);
      float4 b0 = *(const float4*)(biasW + ch * 4);
      a0.x += b0.x; a0.y += b0.y; a0.z += b0.z; a0.w += b0.w;
      int row = row0 + wr * 128 + rr * 32 + rowl;
      *(float4*)(out + (size_t)row * 1024 + colW + ch * 4) = a0;
    }
    LGK(0);
  }
}

// ---------------- merged bias kernel: per block does bias1(t=i) + bias2(s=i)
// grid 2048 1D; XCD-h clustering: xcd = f&7 serves h = {2*xcd, 2*xcd+1}.
__global__ __launch_bounds__(256) void k_bias12(
    const u16* __restrict__ Qb, const u16* __restrict__ Kb,
    const u16* __restrict__ relq, const u16* __restrict__ relk,
    const int* __restrict__ relidx, u16* __restrict__ bias1,
    u16* __restrict__ bias2) {
  const int tid = threadIdx.x, lane = tid & 63, w = tid >> 6;
  const int l15 = lane & 15, l4 = lane >> 4;
  int f = blockIdx.x;
  int seq = (f & 7) * 256 + (f >> 3);
  const int h = seq >> 7, bc = (seq >> 6) & 1, i = seq & 63;
  __shared__ char lds[16640];
  char* RK = lds;
  char* RQ = lds + 8192;
  float* T3 = (float*)(lds + 16384);
  char* wb = lds + w * 4096;  // wave-private bounce (reuses RK/RQ space)
  // ---------- part 1: bias1 for t = i ----------
#pragma unroll
  for (int c = 0; c < 2; c++) {
    int ch = c * 256 + tid;
    int sr = ch >> 3, sl = (ch & 7) ^ (sr & 7);
    int ri = relidx[i * 64 + sr];
    size_t so = ((size_t)h * 225 + ri) * 64 + sl * 8;
    g2l16(relk + so, RK + c * 4096 + w * 1024);
    g2l16(relq + so, RQ + c * 4096 + w * 1024);
  }
  __syncthreads();
  if (tid < 64) {
    int sr = tid;
    float sum = 0.f;
#pragma unroll
    for (int sl = 0; sl < 8; sl++) {
      int o = sr * 128 + ((sl ^ (sr & 7)) << 4);
      bf16x8 aq = *(const bf16x8*)(RQ + o);
      bf16x8 ak = *(const bf16x8*)(RK + o);
#pragma unroll
      for (int j = 0; j < 8; j++) sum += (float)aq[j] * (float)ak[j];
    }
    T3[sr] = sum;
  }
  {
    bf16x8 bfr[4][2];
#pragma unroll
    for (int n = 0; n < 4; n++)
#pragma unroll
      for (int kh = 0; kh < 2; kh++) {
        int r = n * 16 + l15;
        int sl = ((kh << 2) + l4) ^ (r & 7);
        bfr[n][kh] = *(const bf16x8*)(RK + r * 128 + sl * 16);
      }
    __syncthreads();
    f32x4 acc[4][4] = {};
#pragma unroll
    for (int m = 0; m < 4; m++) {
      int bb = bc * 256 + w * 64 + m * 16 + l15;
      const u16* ap = Qb + ((size_t)(bb * 16 + h)) * 4096 + i * 64 + l4 * 8;
      bf16x8 a0 = *(const bf16x8*)ap;
      bf16x8 a1 = *(const bf16x8*)(ap + 32);
#pragma unroll
      for (int n = 0; n < 4; n++) {
        acc[m][n] = MFMA16(a0, bfr[n][0], acc[m][n]);
        acc[m][n] = MFMA16(a1, bfr[n][1], acc[m][n]);
      }
    }
    __syncthreads();  // all waves done reading RK fragments before bounce
#pragma unroll
    for (int m = 0; m < 4; m++) {
#pragma unroll
      for (int n = 0; n < 4; n++)
#pragma unroll
        for (int j = 0; j < 4; j++)
          *(float*)(wb + (l4 * 4 + j) * 256 + (n * 16 + l15) * 4) =
              acc[m][n][j];
      LGK(0);
#pragma unroll
      for (int it = 0; it < 4; it++) {
        int u = it * 64 + lane;
        int row = u >> 4, colf = (u & 15) * 4;
        float4 a0 = *(const float4*)(wb + row * 256 + colf * 4);
        float4 t3 = *(const float4*)(T3 + colf);
        uint2 pk;
        pk.x = (u32)f2bf(a0.x + t3.x) | ((u32)f2bf(a0.y + t3.y) << 16);
        pk.y = (u32)f2bf(a0.z + t3.z) | ((u32)f2bf(a0.w + t3.w) << 16);
        int bb = bc * 256 + w * 64 + m * 16 + row;
        *(uint2*)(bias1 + ((size_t)(bb * 16 + h)) * 4096 + i * 64 + colf) = pk;
      }
      LGK(0);
    }
  }
  __syncthreads();
  // ---------- part 2: bias2 for s = i (gather relq at idx[tq, i]) ----------
#pragma unroll
  for (int c = 0; c < 2; c++) {
    int ch = c * 256 + tid;
    int tq = ch >> 3, sl = (ch & 7) ^ (tq & 7);
    int ri = relidx[tq * 64 + i];
    g2l16(relq + ((size_t)h * 225 + ri) * 64 + sl * 8,
          RK + c * 4096 + w * 1024);
  }
  __syncthreads();
  {
    bf16x8 bfr[4][2];
#pragma unroll
    for (int n = 0; n < 4; n++)
#pragma unroll
      for (int kh = 0; kh < 2; kh++) {
        int r = n * 16 + l15;
        int sl = ((kh << 2) + l4) ^ (r & 7);
        bfr[n][kh] = *(const bf16x8*)(RK + r * 128 + sl * 16);
      }
    f32x4 acc[4][4] = {};
#pragma unroll
    for (int m = 0; m < 4; m++) {
      int bb = bc * 256 + w * 64 + m * 16 + l15;
      const u16* ap = Kb + ((size_t)(bb * 16 + h)) * 4096 + i * 64 + l4 * 8;
      bf16x8 a0 = *(const bf16x8*)ap;
      bf16x8 a1 = *(const bf16x8*)(ap + 32);
#pragma unroll
      for (int n = 0; n < 4; n++) {
        acc[m][n] = MFMA16(a0, bfr[n][0], acc[m][n]);
        acc[m][n] = MFMA16(a1, bfr[n][1], acc[m][n]);
      }
    }
    __syncthreads();  // all waves done reading RK fragments before bounce
#pragma unroll
    for (int m = 0; m < 4; m++) {
#pragma unroll
      for (int n = 0; n < 4; n++)
#pragma unroll
        for (int j = 0; j < 4; j++)
          *(float*)(wb + (l4 * 4 + j) * 256 + (n * 16 + l15) * 4) =
              acc[m][n][j];
      LGK(0);
#pragma unroll
      for (int it = 0; it < 4; it++) {
        int u = it * 64 + lane;
        int row = u >> 4, colf = (u & 15) * 4;
        float4 a0 = *(const float4*)(wb + row * 256 + colf * 4);
        uint2 pk;
        pk.x = (u32)f2bf(a0.x) | ((u32)f2bf(a0.y) << 16);
        pk.y = (u32)f2bf(a0.z) | ((u32)f2bf(a0.w) << 16);
        int bb = bc * 256 + w * 64 + m * 16 + row;
        *(uint2*)(bias2 + ((size_t)(bb * 16 + h)) * 4096 + i * 64 + colf) = pk;
      }
      LGK(0);
    }
  }
}

// ---------------- attention per (b,h): S=QK^T + b1 + b2^T, softmax, P, PV ----
__global__ __launch_bounds__(256) void k_attn(
    const u16* __restrict__ Qb, const u16* __restrict__ Kb,
    const u16* __restrict__ Vb, const u16* __restrict__ b1g,
    const u16* __restrict__ b2g, u16* __restrict__ Pg,
    u16* __restrict__ aout) {
  const int tid = threadIdx.x, lane = tid & 63, w = tid >> 6;
  const int l15 = lane & 15, l4 = lane >> 4;
  const int b = blockIdx.x, h = blockIdx.y;
  __shared__ char lds[49152];
  char* Qt = lds;
  char* Kt = lds + 8192;
  char* Vt = lds + 16384;
  char* B1 = lds + 24576;
  char* B2 = lds + 32768;
  char* Pt = lds + 40960;
  const size_t base = ((size_t)(b * 16 + h)) * 4096;
#pragma unroll
  for (int c = 0; c < 2; c++) {
    int ch = c * 256 + tid;
    int r = ch >> 3, sl = (ch & 7) ^ (r & 7);
    size_t so = base + r * 64 + sl * 8;
    int dst = c * 4096 + w * 1024;
    g2l16(Qb + so, Qt + dst);
    g2l16(Kb + so, Kt + dst);
    g2l16(Vb + so, Vt + dst);
    g2l16(b1g + so, B1 + dst);
    g2l16(b2g + so, B2 + dst);
  }
  __syncthreads();
  f32x4 acc[4] = {};
  bf16x8 qf[2];
  {
    int r = w * 16 + l15;
#pragma unroll
    for (int kh = 0; kh < 2; kh++) {
      int sl = ((kh << 2) + l4) ^ (r & 7);
      qf[kh] = *(const bf16x8*)(Qt + r * 128 + sl * 16);
    }
  }
#pragma unroll
  for (int n = 0; n < 4; n++) {
    int r = n * 16 + l15;
#pragma unroll
    for (int kh = 0; kh < 2; kh++) {
      int sl = ((kh << 2) + l4) ^ (r & 7);
      bf16x8 kf = *(const bf16x8*)(Kt + r * 128 + sl * 16);
      acc[n] = MFMA16(qf[kh], kf, acc[n]);
    }
  }
  const int t0 = w * 16 + l4 * 4;
#pragma unroll
  for (int j = 0; j < 4; j++) {
    int t_ = t0 + j;
    float lv[4];
#pragma unroll
    for (int n = 0; n < 4; n++) {
      int s_ = n * 16 + l15;
      float x = acc[n][j];
      x += bf2f(*(const u16*)(B1 + t_ * 128 + ((s_ * 2) ^ ((t_ & 7) << 4))));
      x += bf2f(*(const u16*)(B2 + s_ * 128 + ((t_ * 2) ^ ((s_ & 7) << 4))));
      lv[n] = x * 0.125f;
    }
    float mx = fmaxf(fmaxf(lv[0], lv[1]), fmaxf(lv[2], lv[3]));
#pragma unroll
    for (int d = 1; d < 16; d <<= 1) mx = fmaxf(mx, __shfl_xor(mx, d, 64));
    float e0 = __expf(lv[0] - mx), e1 = __expf(lv[1] - mx);
    float e2 = __expf(lv[2] - mx), e3 = __expf(lv[3] - mx);
    float sum = e0 + e1 + e2 + e3;
#pragma unroll
    for (int d = 1; d < 16; d <<= 1) sum += __shfl_xor(sum, d, 64);
    float inv = 1.0f / sum;
    float pe[4] = {e0 * inv, e1 * inv, e2 * inv, e3 * inv};
#pragma unroll
    for (int n = 0; n < 4; n++) {
      int s_ = n * 16 + l15;
      *(u16*)(Pt + t_ * 128 + ((s_ * 2) ^ ((t_ & 7) << 4))) = f2bf(pe[n]);
    }
  }
  __syncthreads();
#pragma unroll
  for (int c = 0; c < 2; c++) {
    int ch = c * 256 + tid;
    int r = ch >> 3, sl = ch & 7;
    uint4 v = *(const uint4*)(Pt + r * 128 + ((sl ^ (r & 7)) << 4));
    *((uint4*)(Pg + base) + ch) = v;
  }
  f32x4 acc2[4] = {};
  bf16x8 pf[2];
  {
    int r = w * 16 + l15;
#pragma unroll
    for (int kh = 0; kh < 2; kh++) {
      int sl = ((kh << 2) + l4) ^ (r & 7);
      pf[kh] = *(const bf16x8*)(Pt + r * 128 + sl * 16);
    }
  }
#pragma unroll
  for (int n = 0; n < 4; n++) {
#pragma unroll
    for (int kh = 0; kh < 2; kh++) {
      bf16x8 tmp;
#pragma unroll
      for (int j = 0; j < 8; j++) {
        int s_ = (kh << 5) + (l4 << 3) + j;
        int d_ = n * 16 + l15;
        u16 uu = *(const u16*)(Vt + s_ * 128 + ((d_ * 2) ^ ((s_ & 7) << 4)));
        tmp[j] = __builtin_bit_cast(__bf16, uu);
      }
      acc2[n] = MFMA16(pf[kh], tmp, acc2[n]);
    }
  }
#pragma unroll
  for (int n = 0; n < 4; n++)
#pragma unroll
    for (int j = 0; j < 4; j++) {
      int t_ = t0 + j, d_ = n * 16 + l15;
      aout[((size_t)(b * 64 + t_)) * 1024 + h * 64 + d_] = f2bf(acc2[n][j]);
    }
}

// ---------------- out_relv: aout[b,t,h,d] += sum_s P[b,s]*rel_v[idx[t,s],d]
// grid 2048 1D with XCD-h clustering (same decode as k_bias12).
__global__ __launch_bounds__(256) void k_relv(
    const u16* __restrict__ Pg, const u16* __restrict__ relv,
    const int* __restrict__ relidx, u16* __restrict__ aout) {
  const int tid = threadIdx.x, lane = tid & 63, w = tid >> 6;
  const int l15 = lane & 15, l4 = lane >> 4;
  int f = blockIdx.x;
  int seq = (f & 7) * 256 + (f >> 3);
  const int h = seq >> 7, bc = (seq >> 6) & 1, t = seq & 63;
  __shared__ char lds[8192];
#pragma unroll
  for (int c = 0; c < 2; c++) {
    int ch = c * 256 + tid;
    int sr = ch >> 3, sl = (ch & 7) ^ (sr & 7);
    int ri = relidx[t * 64 + sr];
    g2l16(relv + ((size_t)h * 225 + ri) * 64 + sl * 8,
          lds + c * 4096 + w * 1024);
  }
  __syncthreads();
  bf16x8 bfr[4][2];
#pragma unroll
  for (int n = 0; n < 4; n++)
#pragma unroll
    for (int kh = 0; kh < 2; kh++) {
      bf16x8 tmp;
#pragma unroll
      for (int j = 0; j < 8; j++) {
        int s_ = (kh << 5) + (l4 << 3) + j;
        int d_ = n * 16 + l15;
        u16 u = *(const u16*)(lds + s_ * 128 + ((d_ * 2) ^ ((s_ & 7) << 4)));
        tmp[j] = __builtin_bit_cast(__bf16, u);
      }
      bfr[n][kh] = tmp;
    }
  f32x4 acc[4][4] = {};
#pragma unroll
  for (int m = 0; m < 4; m++) {
    int bb = bc * 256 + w * 64 + m * 16 + l15;
    const u16* ap = Pg + ((size_t)(bb * 16 + h)) * 4096 + t * 64 + l4 * 8;
    bf16x8 a0 = *(const bf16x8*)ap;
    bf16x8 a1 = *(const bf16x8*)(ap + 32);
#pragma unroll
    for (int n = 0; n < 4; n++) {
      acc[m][n] = MFMA16(a0, bfr[n][0], acc[m][n]);
      acc[m][n] = MFMA16(a1, bfr[n][1], acc[m][n]);
    }
  }
#pragma unroll
  for (int m = 0; m < 4; m++)
#pragma unroll
    for (int n = 0; n < 4; n++)
#pragma unroll
      for (int j = 0; j < 4; j++) {
        int bb = bc * 256 + w * 64 + m * 16 + l4 * 4 + j;
        int d_ = n * 16 + l15;
        size_t o = ((size_t)(bb * 64 + t)) * 1024 + h * 64 + d_;
        aout[o] = f2bf(bf2f(aout[o]) + acc[m][n][j]);
      }
}

extern "C" void kernel_launch(void* const* d_in, const int* in_sizes, int n_in,
                              void* d_out, int out_size, void* d_ws,
                              size_t ws_size, hipStream_t stream) {
  const float* x = (const float*)d_in[0];
  const float* Wq = (const float*)d_in[1];
  const float* bq = (const float*)d_in[2];
  const float* Wk = (const float*)d_in[3];
  const float* bk = (const float*)d_in[4];
  const float* Wv = (const float*)d_in[5];
  const float* bv = (const float*)d_in[6];
  const float* Wo = (const float*)d_in[7];
  const float* bo = (const float*)d_in[8];
  const float* rq = (const float*)d_in[9];
  const float* rk = (const float*)d_in[10];
  const float* rv = (const float*)d_in[11];
  const int* ridx = (const int*)d_in[12];
  float* out = (float*)d_out;

  char* ws = (char*)d_ws;
  const size_t MB = 1ull << 20;
  u16* xb = (u16*)(ws + 0);  // reused as P after k_gemm_qkv consumes it
  u16* Qb = (u16*)(ws + 64 * MB);
  u16* Kb = (u16*)(ws + 128 * MB);
  u16* Vb = (u16*)(ws + 192 * MB);
  u16* b1 = (u16*)(ws + 256 * MB);
  u16* b2 = (u16*)(ws + 320 * MB);
  u16* aout = (u16*)(ws + 384 * MB);
  u16* wqkv = (u16*)(ws + 448 * MB);
  u16* wo = (u16*)(ws + 454 * MB);
  u16* relq = (u16*)(ws + 456 * MB);
  u16* relk = (u16*)(ws + 457 * MB);
  u16* relv = (u16*)(ws + 458 * MB);
  u16* Pg = xb;

  k_cvt<<<32768, 256, 0, stream>>>(x, xb, 8388608);
  k_cvt7<<<dim3(1024, 7), 256, 0, stream>>>(
      Wq, Wk, Wv, Wo, rq, rk, rv, wqkv, wqkv + 1048576, wqkv + 2097152, wo,
      relq, relk, relv);

  k_gemm_qkv<<<1536, 512, 0, stream>>>(xb, wqkv, bq, bk, bv, Qb, Kb, Vb);
  k_bias12<<<2048, 256, 0, stream>>>(Qb, Kb, relq, relk, ridx, b1, b2);
  k_attn<<<dim3(512, 16), 256, 0, stream>>>(Qb, Kb, Vb, b1, b2, Pg, aout);
  k_relv<<<2048, 256, 0, stream>>>(Pg, relv, ridx, aout);
  k_gemm_out<<<512, 512, 0, stream>>>(aout, wo, bo, out);
}